// Round 1
// baseline (579.040 us; speedup 1.0000x reference)
//
#include <hip/hip_runtime.h>
#include <hip/hip_bf16.h>
#include <math.h>

#define T_DIM 512
#define B_DIM 32
#define V_DIM 4096
#define LMAX 32
#define S_DIM (2 * LMAX + 1)   // 65
#define NEG (-1e30f)

// ---------------------------------------------------------------------------
// Kernel 0: build extended label sequence (blanks interleaved) + can_skip.
// ext[b][s]: s even -> 0 (blank); s odd -> labels[offset_b + s>>1] if in range.
// can_skip[b][s] = (s>=2) && ext!=0 && ext != ext[s-2]
// ---------------------------------------------------------------------------
__global__ void k_ext(const int* __restrict__ labels,
                      const int* __restrict__ label_lens,
                      int total,
                      int* __restrict__ ext,
                      int* __restrict__ canskip) {
    int idx = blockIdx.x * blockDim.x + threadIdx.x;
    if (idx >= B_DIM * S_DIM) return;
    int b = idx / S_DIM;
    int s = idx % S_DIM;
    int off = 0;
    for (int i = 0; i < b; ++i) off += label_lens[i];
    int len = label_lens[b];

    auto getext = [&](int ss) -> int {
        if ((ss & 1) == 0) return 0;           // blank
        int j = ss >> 1;                        // (ss-1)/2 for odd ss
        if (j >= len) return 0;
        int id = off + j;
        if (id > total - 1) id = total - 1;
        if (id < 0) id = 0;
        return labels[id];
    };

    int e = getext(s);
    ext[idx] = e;
    int cs = 0;
    if (s >= 2) {
        int em2 = getext(s - 2);
        cs = (e != 0 && e != em2) ? 1 : 0;
    }
    canskip[idx] = cs;
}

// ---------------------------------------------------------------------------
// Kernel 1: per (t,b) row of acts (V=4096 floats): compute logZ = logsumexp,
// then emit[t,b,s] = acts[t,b,ext[b,s]] - logZ for s in [0,65).
// One block (256 threads) per row; 16 floats/thread via float4.
// ---------------------------------------------------------------------------
__global__ __launch_bounds__(256) void k_logz_emit(const float* __restrict__ acts,
                                                   const int* __restrict__ ext,
                                                   float* __restrict__ emit) {
    int bid = blockIdx.x;              // = t*B + b
    int b = bid % B_DIM;
    const float* row = acts + (size_t)bid * V_DIM;
    int tid = threadIdx.x;

    const float4* row4 = reinterpret_cast<const float4*>(row);
    float4 v[4];
#pragma unroll
    for (int k = 0; k < 4; ++k) v[k] = row4[tid + k * 256];

    // row max
    float mx = -INFINITY;
#pragma unroll
    for (int k = 0; k < 4; ++k) {
        mx = fmaxf(mx, fmaxf(fmaxf(v[k].x, v[k].y), fmaxf(v[k].z, v[k].w)));
    }
#pragma unroll
    for (int off = 32; off > 0; off >>= 1) mx = fmaxf(mx, __shfl_xor(mx, off));

    __shared__ float smax[4];
    __shared__ float ssum[4];
    int wave = tid >> 6;
    int lane = tid & 63;
    if (lane == 0) smax[wave] = mx;
    __syncthreads();
    mx = fmaxf(fmaxf(smax[0], smax[1]), fmaxf(smax[2], smax[3]));

    // sum exp
    float s = 0.f;
#pragma unroll
    for (int k = 0; k < 4; ++k) {
        s += expf(v[k].x - mx);
        s += expf(v[k].y - mx);
        s += expf(v[k].z - mx);
        s += expf(v[k].w - mx);
    }
#pragma unroll
    for (int off = 32; off > 0; off >>= 1) s += __shfl_xor(s, off);
    if (lane == 0) ssum[wave] = s;
    __syncthreads();
    s = ssum[0] + ssum[1] + ssum[2] + ssum[3];

    float logZ = mx + logf(s);

    if (tid < S_DIM) {
        int lab = ext[b * S_DIM + tid];
        emit[(size_t)bid * S_DIM + tid] = row[lab] - logZ;
    }
}

// ---------------------------------------------------------------------------
// Kernel 2: CTC forward recursion. One block = one wave = one example.
// Lane l holds state s=l; lane-uniform register a64 holds state 64 (always a
// blank -> no skip transition). Neighbor alphas via __shfl_up (old values).
// Ragged time lengths: freeze alpha once t >= act_len.
// ---------------------------------------------------------------------------
__global__ __launch_bounds__(64) void k_forward(const float* __restrict__ emit,
                                                const int* __restrict__ canskip,
                                                const int* __restrict__ act_lens,
                                                const int* __restrict__ label_lens,
                                                float* __restrict__ losses) {
    int b = blockIdx.x;
    int l = threadIdx.x;           // 0..63 == state index
    int len = label_lens[b];
    int alen = act_lens[b];
    int Svalid = 2 * len + 1;
    bool valid = l < Svalid;
    bool valid64 = 64 < Svalid;    // only when len == 32
    bool skip = canskip[b * S_DIM + l] != 0;

    // t = 0 init
    {
        const float* p0 = emit + (size_t)b * S_DIM;   // t=0 row
        float e0 = p0[l];
        bool init = (l <= 1) && valid;
        // alpha
        // (state 64 is never s<=1 -> NEG)
        // note: invalid states stay NEG forever (we re-mask each step)
        // all lanes keep a64 identically (uniform recursion) for easy readout
        float a_init = init ? e0 : NEG;
        // fallthrough into loop with registers:
        float a = a_init;
        float a64 = NEG;

        for (int t0 = 1; t0 < T_DIM; t0 += 4) {
            float e[4], e64[4];
#pragma unroll
            for (int i = 0; i < 4; ++i) {
                int t = t0 + i;
                if (t < T_DIM) {
                    const float* p = emit + ((size_t)t * B_DIM + b) * S_DIM;
                    e[i] = p[l];
                    e64[i] = p[64];     // broadcast load (same addr all lanes)
                } else {
                    e[i] = 0.f; e64[i] = 0.f;
                }
            }
#pragma unroll
            for (int i = 0; i < 4; ++i) {
                int t = t0 + i;
                if (t >= T_DIM) break;
                float am1 = __shfl_up(a, 1);
                float am2 = __shfl_up(a, 2);
                float prev63 = __shfl(a, 63);
                float a1 = (l >= 1) ? am1 : NEG;
                float a2 = skip ? am2 : NEG;
                float m = fmaxf(a, fmaxf(a1, a2));
                float nw = m + logf(expf(a - m) + expf(a1 - m) + expf(a2 - m)) + e[i];
                nw = valid ? nw : NEG;
                // state 64 (blank): transitions from itself and state 63
                float m2 = fmaxf(a64, prev63);
                float nw64 = m2 + logf(expf(a64 - m2) + expf(prev63 - m2)) + e64[i];
                nw64 = valid64 ? nw64 : NEG;
                bool run = t < alen;
                a = run ? nw : a;
                a64 = run ? nw64 : a64;
            }
        }

        // readout: loss = -logaddexp(alpha[end], alpha[end-1]), end = 2*len
        int end = 2 * len;
        float a_end_sh = __shfl(a, end & 63);
        float l1 = (end == 64) ? a64 : a_end_sh;
        int em1 = end - 1; if (em1 < 0) em1 = 0;
        float l2 = __shfl(a, em1);
        float m = fmaxf(l1, l2);
        float loss = -(m + logf(expf(l1 - m) + expf(l2 - m)));
        if (l == 0) losses[b] = loss;
    }
}

// ---------------------------------------------------------------------------
// Kernel 3: sum per-example losses -> d_out[0]
// ---------------------------------------------------------------------------
__global__ void k_sum(const float* __restrict__ losses, float* __restrict__ out) {
    int l = threadIdx.x;
    float v = (l < B_DIM) ? losses[l] : 0.f;
#pragma unroll
    for (int off = 32; off > 0; off >>= 1) v += __shfl_xor(v, off);
    if (l == 0) out[0] = v;
}

// ---------------------------------------------------------------------------
extern "C" void kernel_launch(void* const* d_in, const int* in_sizes, int n_in,
                              void* d_out, int out_size, void* d_ws, size_t ws_size,
                              hipStream_t stream) {
    const float* acts      = (const float*)d_in[0];
    const int*   labels    = (const int*)d_in[1];
    const int*   act_lens  = (const int*)d_in[2];
    const int*   label_lens= (const int*)d_in[3];
    int total_labels = in_sizes[1];

    char* ws = (char*)d_ws;
    // layout: ext [B*S int] | canskip [B*S int] | losses [B float] | emit [T*B*S float]
    int*   ext     = (int*)(ws);
    int*   canskip = (int*)(ws + 8320);          // B*S*4 = 8320
    float* losses  = (float*)(ws + 16640);
    float* emit    = (float*)(ws + 16768);       // 16-byte aligned
    float* out     = (float*)d_out;

    k_ext<<<(B_DIM * S_DIM + 255) / 256, 256, 0, stream>>>(labels, label_lens,
                                                           total_labels, ext, canskip);
    k_logz_emit<<<T_DIM * B_DIM, 256, 0, stream>>>(acts, ext, emit);
    k_forward<<<B_DIM, 64, 0, stream>>>(emit, canskip, act_lens, label_lens, losses);
    k_sum<<<1, 64, 0, stream>>>(losses, out);
}

// Round 2
// 534.467 us; speedup vs baseline: 1.0834x; 1.0834x over previous
//
#include <hip/hip_runtime.h>
#include <hip/hip_bf16.h>
#include <math.h>

#define T_DIM 512
#define B_DIM 32
#define V_DIM 4096
#define LMAX 32
#define S_DIM (2 * LMAX + 1)   // 65
#define NEG (-1e30f)

// ---------------------------------------------------------------------------
// Kernel 0: build extended label sequence (blanks interleaved) + can_skip.
// ---------------------------------------------------------------------------
__global__ void k_ext(const int* __restrict__ labels,
                      const int* __restrict__ label_lens,
                      int total,
                      int* __restrict__ ext,
                      int* __restrict__ canskip) {
    int idx = blockIdx.x * blockDim.x + threadIdx.x;
    if (idx >= B_DIM * S_DIM) return;
    int b = idx / S_DIM;
    int s = idx % S_DIM;
    int off = 0;
    for (int i = 0; i < b; ++i) off += label_lens[i];
    int len = label_lens[b];

    auto getext = [&](int ss) -> int {
        if ((ss & 1) == 0) return 0;           // blank
        int j = ss >> 1;
        if (j >= len) return 0;
        int id = off + j;
        if (id > total - 1) id = total - 1;
        if (id < 0) id = 0;
        return labels[id];
    };

    int e = getext(s);
    ext[idx] = e;
    int cs = 0;
    if (s >= 2) {
        int em2 = getext(s - 2);
        cs = (e != 0 && e != em2) ? 1 : 0;
    }
    canskip[idx] = cs;
}

// ---------------------------------------------------------------------------
// Kernel 1: per (t,b) row of acts (V=4096): logZ = logsumexp, then write
//   emitA[b][t][s]  for s in [0,64)   (lane-contiguous for k_forward)
//   emit64[b][t]    for s == 64       (uniform per-wave stream)
// ---------------------------------------------------------------------------
__global__ __launch_bounds__(256) void k_logz_emit(const float* __restrict__ acts,
                                                   const int* __restrict__ ext,
                                                   float* __restrict__ emitA,
                                                   float* __restrict__ emit64) {
    int bid = blockIdx.x;              // = t*B + b
    int t = bid / B_DIM;
    int b = bid % B_DIM;
    const float* row = acts + (size_t)bid * V_DIM;
    int tid = threadIdx.x;

    const float4* row4 = reinterpret_cast<const float4*>(row);
    float4 v[4];
#pragma unroll
    for (int k = 0; k < 4; ++k) v[k] = row4[tid + k * 256];

    float mx = -INFINITY;
#pragma unroll
    for (int k = 0; k < 4; ++k) {
        mx = fmaxf(mx, fmaxf(fmaxf(v[k].x, v[k].y), fmaxf(v[k].z, v[k].w)));
    }
#pragma unroll
    for (int off = 32; off > 0; off >>= 1) mx = fmaxf(mx, __shfl_xor(mx, off));

    __shared__ float smax[4];
    __shared__ float ssum[4];
    int wave = tid >> 6;
    int lane = tid & 63;
    if (lane == 0) smax[wave] = mx;
    __syncthreads();
    mx = fmaxf(fmaxf(smax[0], smax[1]), fmaxf(smax[2], smax[3]));

    float s = 0.f;
#pragma unroll
    for (int k = 0; k < 4; ++k) {
        s += expf(v[k].x - mx);
        s += expf(v[k].y - mx);
        s += expf(v[k].z - mx);
        s += expf(v[k].w - mx);
    }
#pragma unroll
    for (int off = 32; off > 0; off >>= 1) s += __shfl_xor(s, off);
    if (lane == 0) ssum[wave] = s;
    __syncthreads();
    s = ssum[0] + ssum[1] + ssum[2] + ssum[3];

    float logZ = mx + logf(s);

    if (tid < 64) {
        int lab = ext[b * S_DIM + tid];
        emitA[((size_t)b * T_DIM + t) * 64 + tid] = row[lab] - logZ;
    } else if (tid == 64) {
        int lab = ext[b * S_DIM + 64];   // always blank (0)
        emit64[(size_t)b * T_DIM + t] = row[lab] - logZ;
    }
}

// ---------------------------------------------------------------------------
// Kernel 2: CTC forward recursion. One wave per example; lane = state.
// 8-deep software-pipelined prefetch on a contiguous [b][t][64] stream.
// Early-exits at act_len (bit-identical: frozen steps were discarded).
// State 64 (only when len==32) handled in a wave-uniform side chain.
// ---------------------------------------------------------------------------
#define PFD 8
__global__ __launch_bounds__(64) void k_forward(const float* __restrict__ emitA,
                                                const float* __restrict__ emit64,
                                                const int* __restrict__ canskip,
                                                const int* __restrict__ act_lens,
                                                const int* __restrict__ label_lens,
                                                float* __restrict__ losses) {
    int b = blockIdx.x;
    int l = threadIdx.x;           // 0..63 == state index
    int len = label_lens[b];
    int alen = act_lens[b];
    int Svalid = 2 * len + 1;
    bool valid = l < Svalid;
    bool has64 = (len == LMAX);    // state 64 exists only when len == 32
    bool skip = canskip[b * S_DIM + l] != 0;

    const float* pb  = emitA + (size_t)b * T_DIM * 64 + l;
    const float* p64 = emit64 + (size_t)b * T_DIM;

    // t = 0 init
    float a   = ((l <= 1) && valid) ? pb[0] : NEG;
    float a64 = NEG;

    float cur[PFD], cur64[PFD];
#pragma unroll
    for (int i = 0; i < PFD; ++i) {
        int t = 1 + i; int tc = (t < T_DIM) ? t : (T_DIM - 1);
        cur[i]   = pb[(size_t)tc * 64];
        cur64[i] = has64 ? p64[tc] : 0.f;
    }

    for (int t0 = 1; t0 < alen; t0 += PFD) {
        float nxt[PFD], nxt64[PFD];
#pragma unroll
        for (int i = 0; i < PFD; ++i) {
            int t = t0 + PFD + i; int tc = (t < T_DIM) ? t : (T_DIM - 1);
            nxt[i]   = pb[(size_t)tc * 64];
            nxt64[i] = has64 ? p64[tc] : 0.f;
        }
#pragma unroll
        for (int i = 0; i < PFD; ++i) {
            int t = t0 + i;
            if (t < alen) {
                float am1 = __shfl_up(a, 1);
                float am2 = __shfl_up(a, 2);
                float a1 = (l >= 1) ? am1 : NEG;
                float a2 = skip ? am2 : NEG;
                float m = fmaxf(a, fmaxf(a1, a2));
                float nw = m + logf(expf(a - m) + expf(a1 - m) + expf(a2 - m)) + cur[i];
                nw = valid ? nw : NEG;
                if (has64) {
                    float prev63 = __shfl(a, 63);
                    float m2 = fmaxf(a64, prev63);
                    a64 = m2 + logf(expf(a64 - m2) + expf(prev63 - m2)) + cur64[i];
                }
                a = nw;
            }
        }
#pragma unroll
        for (int i = 0; i < PFD; ++i) { cur[i] = nxt[i]; cur64[i] = nxt64[i]; }
    }

    // readout: loss = -logaddexp(alpha[end], alpha[end-1]), end = 2*len
    int end = 2 * len;
    float l1, l2;
    if (end == 64) {
        l1 = a64;
        l2 = __shfl(a, 63);
    } else {
        l1 = __shfl(a, end);
        l2 = __shfl(a, end - 1);
    }
    float m = fmaxf(l1, l2);
    float loss = -(m + logf(expf(l1 - m) + expf(l2 - m)));
    if (l == 0) losses[b] = loss;
}

// ---------------------------------------------------------------------------
// Kernel 3: sum per-example losses -> d_out[0]
// ---------------------------------------------------------------------------
__global__ void k_sum(const float* __restrict__ losses, float* __restrict__ out) {
    int l = threadIdx.x;
    float v = (l < B_DIM) ? losses[l] : 0.f;
#pragma unroll
    for (int off = 32; off > 0; off >>= 1) v += __shfl_xor(v, off);
    if (l == 0) out[0] = v;
}

// ---------------------------------------------------------------------------
extern "C" void kernel_launch(void* const* d_in, const int* in_sizes, int n_in,
                              void* d_out, int out_size, void* d_ws, size_t ws_size,
                              hipStream_t stream) {
    const float* acts       = (const float*)d_in[0];
    const int*   labels     = (const int*)d_in[1];
    const int*   act_lens   = (const int*)d_in[2];
    const int*   label_lens = (const int*)d_in[3];
    int total_labels = in_sizes[1];

    char* ws = (char*)d_ws;
    // layout: ext [B*S int] | canskip [B*S int] | losses [B f32] | emitA | emit64
    int*   ext     = (int*)(ws);
    int*   canskip = (int*)(ws + 8320);                 // B*S*4 = 8320
    float* losses  = (float*)(ws + 16640);
    float* emitA   = (float*)(ws + 16768);              // B*T*64*4 = 4 MiB
    float* emit64  = (float*)(ws + 16768 + 4194304);    // B*T*4   = 64 KiB
    float* out     = (float*)d_out;

    k_ext<<<(B_DIM * S_DIM + 255) / 256, 256, 0, stream>>>(labels, label_lens,
                                                           total_labels, ext, canskip);
    k_logz_emit<<<T_DIM * B_DIM, 256, 0, stream>>>(acts, ext, emitA, emit64);
    k_forward<<<B_DIM, 64, 0, stream>>>(emitA, emit64, canskip, act_lens,
                                        label_lens, losses);
    k_sum<<<1, 64, 0, stream>>>(losses, out);
}

// Round 6
// 431.569 us; speedup vs baseline: 1.3417x; 1.2384x over previous
//
#include <hip/hip_runtime.h>
#include <hip/hip_bf16.h>
#include <math.h>

#define T_DIM 512
#define B_DIM 32
#define V_DIM 4096
#define LMAX 32
#define S_DIM 65            // 2*LMAX+1
#define NEG (-1e30f)
#define EROWS 528           // T_DIM + 16 pad rows (prefetch overruns read finite 0xAA poison)
#define LOG2E 1.4426950408889634f
#define LN2   0.6931471805599453f

// ---- raw hardware transcendentals (v_exp_f32 IS exp2; v_log_f32 IS log2) ----
__device__ __forceinline__ float fexp2(float x) {
#if __has_builtin(__builtin_amdgcn_exp2f)
    return __builtin_amdgcn_exp2f(x);
#else
    return exp2f(x);
#endif
}
__device__ __forceinline__ float flog2(float x) {
#if __has_builtin(__builtin_amdgcn_logf)
    return __builtin_amdgcn_logf(x);
#else
    return log2f(x);
#endif
}
// force global_load (vmcnt-only; never flat_load which also bumps lgkmcnt)
__device__ __forceinline__ float gload(const float* p) {
    return *(const __attribute__((address_space(1))) float*)((unsigned long long)p);
}
__device__ __forceinline__ float lse2_2(float x, float y) {
    float m = fmaxf(x, y);
    return m + flog2(fexp2(x - m) + fexp2(y - m));
}
__device__ __forceinline__ float lse3_2(float x, float y, float z) {
    float m = fmaxf(x, fmaxf(y, z));
    return m + flog2(fexp2(x - m) + fexp2(y - m) + fexp2(z - m));
}

// ---------------------------------------------------------------------------
// Kernel 0: extended labels + can_skip.
// ---------------------------------------------------------------------------
__global__ void k_ext(const int* __restrict__ labels,
                      const int* __restrict__ label_lens,
                      int total,
                      int* __restrict__ ext,
                      int* __restrict__ canskip) {
    int idx = blockIdx.x * blockDim.x + threadIdx.x;
    if (idx >= B_DIM * S_DIM) return;
    int b = idx / S_DIM;
    int s = idx % S_DIM;
    int off = 0;
    for (int i = 0; i < b; ++i) off += label_lens[i];
    int len = label_lens[b];

    auto getext = [&](int ss) -> int {
        if ((ss & 1) == 0) return 0;
        int j = ss >> 1;
        if (j >= len) return 0;
        int id = off + j;
        if (id > total - 1) id = total - 1;
        if (id < 0) id = 0;
        return labels[id];
    };

    int e = getext(s);
    ext[idx] = e;
    int cs = 0;
    if (s >= 2) {
        int em2 = getext(s - 2);
        cs = (e != 0 && e != em2) ? 1 : 0;
    }
    canskip[idx] = cs;
}

// ---------------------------------------------------------------------------
// Kernel 1: per (t,b) row: logZ (log2 domain, HW exp2/log2) + gather emissions
//   emitA[b][t][0..64) , emit64[b][t]  — all pre-scaled by log2(e).
// ---------------------------------------------------------------------------
__global__ __launch_bounds__(256) void k_logz_emit(const float* __restrict__ acts,
                                                   const int* __restrict__ ext,
                                                   float* __restrict__ emitA,
                                                   float* __restrict__ emit64) {
    int bid = blockIdx.x;              // = t*B + b
    int t = bid / B_DIM;
    int b = bid % B_DIM;
    const float* row = acts + (size_t)bid * V_DIM;
    int tid = threadIdx.x;

    const float4* row4 = reinterpret_cast<const float4*>(row);
    float4 v[4];
#pragma unroll
    for (int k = 0; k < 4; ++k) v[k] = row4[tid + k * 256];

    float mx = -INFINITY;
#pragma unroll
    for (int k = 0; k < 4; ++k)
        mx = fmaxf(mx, fmaxf(fmaxf(v[k].x, v[k].y), fmaxf(v[k].z, v[k].w)));
#pragma unroll
    for (int off = 32; off > 0; off >>= 1) mx = fmaxf(mx, __shfl_xor(mx, off));

    __shared__ float smax[4], ssum[4];
    int wave = tid >> 6, lane = tid & 63;
    if (lane == 0) smax[wave] = mx;
    __syncthreads();
    mx = fmaxf(fmaxf(smax[0], smax[1]), fmaxf(smax[2], smax[3]));

    float mxL = mx * LOG2E;
    float s = 0.f;
#pragma unroll
    for (int k = 0; k < 4; ++k) {
        s += fexp2(fmaf(v[k].x, LOG2E, -mxL));
        s += fexp2(fmaf(v[k].y, LOG2E, -mxL));
        s += fexp2(fmaf(v[k].z, LOG2E, -mxL));
        s += fexp2(fmaf(v[k].w, LOG2E, -mxL));
    }
#pragma unroll
    for (int off = 32; off > 0; off >>= 1) s += __shfl_xor(s, off);
    if (lane == 0) ssum[wave] = s;
    __syncthreads();
    s = ssum[0] + ssum[1] + ssum[2] + ssum[3];

    float logZ2 = mxL + flog2(s);

    if (tid < 64) {
        int lab = ext[b * S_DIM + tid];
        emitA[((size_t)b * EROWS + t) * 64 + tid] = fmaf(row[lab], LOG2E, -logZ2);
    } else if (tid == 64) {
        // state 64 is always blank (label 0)
        emit64[(size_t)b * EROWS + t] = fmaf(row[0], LOG2E, -logZ2);
    }
}

// ---------------------------------------------------------------------------
// Kernel 2: CTC forward. One wave/example, lane=state. Two time-steps per
// shuffle round (distances 1..4 in parallel); state 64 kept in lane 63's
// registers; log2-domain lse via hardware exp2/log2; windowed prefetch of 8
// timesteps via forced global_loads (vmcnt-only, off the lgkm chain).
// Fixed 256-round trip; ragged lengths via per-step freeze selects.
// ---------------------------------------------------------------------------
__global__ __launch_bounds__(64) void k_forward(const float* __restrict__ emitA,
                                                const float* __restrict__ emit64,
                                                const int* __restrict__ canskip,
                                                const int* __restrict__ act_lens,
                                                const int* __restrict__ label_lens,
                                                float* __restrict__ losses) {
    int b = blockIdx.x;
    int l = threadIdx.x;           // lane == state index (0..63)
    int len = label_lens[b];
    int alen = act_lens[b];
    int Svalid = 2 * len + 1;
    bool validS  = l < Svalid;
    bool validM1 = (l >= 1) && (l - 1 < Svalid);
    bool validM2 = (l >= 2) && (l - 2 < Svalid);
    const int* csb = canskip + b * S_DIM;
    bool skipS  = csb[l] != 0;
    bool skipM1 = (l >= 1) ? (csb[l - 1] != 0) : false;
    bool skipM2 = (l >= 2) ? (csb[l - 2] != 0) : false;

    const float* pb  = emitA + (size_t)b * EROWS * 64;
    const float* p64 = emit64 + (size_t)b * EROWS;
    int lm1 = (l >= 1) ? l - 1 : 0;
    int lm2 = (l >= 2) ? l - 2 : 0;

    float a   = (l <= 1 && validS) ? gload(pb + l) : NEG;
    float a64 = NEG;     // meaningful in lane 63 only

    float c0[4], cm1[4], cm2[4], c1[4], ca64[4], cb64[4];

#define LOADW(d0, dm1, dm2, d1, d64a, d64b, TB)                                 \
    _Pragma("unroll")                                                           \
    for (int r = 0; r < 4; ++r) {                                               \
        int tt = (TB) + 2 * r;                                                  \
        const float* rowp = pb + (size_t)tt * 64;                               \
        d0[r]   = gload(rowp + l);                                              \
        dm1[r]  = gload(rowp + lm1);                                            \
        dm2[r]  = gload(rowp + lm2);                                            \
        d1[r]   = gload(rowp + 64 + l);                                         \
        d64a[r] = gload(p64 + tt);                                              \
        d64b[r] = gload(p64 + tt + 1);                                          \
    }

    LOADW(c0, cm1, cm2, c1, ca64, cb64, 1)

    for (int w = 0; w < 64; ++w) {
        float n0[4], nm1[4], nm2[4], n1[4], na64[4], nb64[4];
        LOADW(n0, nm1, nm2, n1, na64, nb64, 1 + 8 * (w + 1))
#pragma unroll
        for (int r = 0; r < 4; ++r) {
            int t = 1 + 8 * w + 2 * r;          // this round covers steps t, t+1
            float am1 = __shfl_up(a, 1); am1 = (l >= 1) ? am1 : NEG;
            float am2 = __shfl_up(a, 2); am2 = (l >= 2) ? am2 : NEG;
            float am3 = __shfl_up(a, 3); am3 = (l >= 3) ? am3 : NEG;
            float am4 = __shfl_up(a, 4); am4 = (l >= 4) ? am4 : NEG;
            // time t intermediates (states s, s-1, s-2 computed in lane s)
            float b0 = lse3_2(a,   am1, skipS  ? am2 : NEG) + c0[r];
            b0 = validS ? b0 : NEG;
            float b1 = lse3_2(am1, am2, skipM1 ? am3 : NEG) + cm1[r];
            b1 = validM1 ? b1 : NEG;
            float b2 = lse3_2(am2, am3, skipM2 ? am4 : NEG) + cm2[r];
            b2 = validM2 ? b2 : NEG;
            // time t+1
            float cc = lse3_2(b0, b1, skipS ? b2 : NEG) + c1[r];
            cc = validS ? cc : NEG;
            // state-64 chain (correct only in lane 63; others discarded)
            float t64a = lse2_2(a64, a) + ca64[r];
            float t64b = lse2_2(t64a, b0) + cb64[r];
            bool r1 = t < alen, r2 = (t + 1) < alen;
            a   = r2 ? cc   : (r1 ? b0   : a);
            a64 = r2 ? t64b : (r1 ? t64a : a64);
        }
#pragma unroll
        for (int r = 0; r < 4; ++r) {
            c0[r] = n0[r]; cm1[r] = nm1[r]; cm2[r] = nm2[r]; c1[r] = n1[r];
            ca64[r] = na64[r]; cb64[r] = nb64[r];
        }
    }
#undef LOADW

    // loss = -ln2 * log2addexp(alpha[end], alpha[end-1]), end = 2*len
    int end = 2 * len;
    float v64 = __shfl(a64, 63);
    float ae  = __shfl(a, end & 63);
    float l1 = (end == 64) ? v64 : ae;
    float l2 = __shfl(a, end - 1);
    float m = fmaxf(l1, l2);
    float loss = -LN2 * (m + flog2(fexp2(l1 - m) + fexp2(l2 - m)));
    if (l == 0) losses[b] = loss;
}

// ---------------------------------------------------------------------------
// Kernel 3: sum per-example losses -> d_out[0]
// ---------------------------------------------------------------------------
__global__ void k_sum(const float* __restrict__ losses, float* __restrict__ out) {
    int l = threadIdx.x;
    float v = (l < B_DIM) ? losses[l] : 0.f;
#pragma unroll
    for (int off = 32; off > 0; off >>= 1) v += __shfl_xor(v, off);
    if (l == 0) out[0] = v;
}

// ---------------------------------------------------------------------------
extern "C" void kernel_launch(void* const* d_in, const int* in_sizes, int n_in,
                              void* d_out, int out_size, void* d_ws, size_t ws_size,
                              hipStream_t stream) {
    const float* acts       = (const float*)d_in[0];
    const int*   labels     = (const int*)d_in[1];
    const int*   act_lens   = (const int*)d_in[2];
    const int*   label_lens = (const int*)d_in[3];
    int total_labels = in_sizes[1];

    char* ws = (char*)d_ws;
    // ext [B*S i32] | canskip [B*S i32] | losses [B f32] | emitA [B*EROWS*64 f32] | emit64 [B*EROWS f32]
    int*   ext     = (int*)(ws);
    int*   canskip = (int*)(ws + 8320);
    float* losses  = (float*)(ws + 16640);
    float* emitA   = (float*)(ws + 16768);
    float* emit64  = (float*)(ws + 16768 + (size_t)B_DIM * EROWS * 64 * 4);
    float* out     = (float*)d_out;

    k_ext<<<(B_DIM * S_DIM + 255) / 256, 256, 0, stream>>>(labels, label_lens,
                                                           total_labels, ext, canskip);
    k_logz_emit<<<T_DIM * B_DIM, 256, 0, stream>>>(acts, ext, emitA, emit64);
    k_forward<<<B_DIM, 64, 0, stream>>>(emitA, emit64, canskip, act_lens,
                                        label_lens, losses);
    k_sum<<<1, 64, 0, stream>>>(losses, out);
}